// Round 4
// baseline (244.791 us; speedup 1.0000x reference)
//
#include <hip/hip_runtime.h>

#define IMG_H 512
#define IMG_W 512
#define N_IMG 24                         // B*C
#define NPIX (N_IMG * IMG_H * IMG_W)     // 6291456

#define TW 128                           // tile width in px
#define TH 8                             // tile height in px
#define LW (TW + 8)                      // 136 floats per LDS row (16B-aligned stride)
#define LH (TH + 4)                      // 12 LDS rows (2-row halo each side)
#define BLOCK 256
#define TILES_W (IMG_W / TW)             // 4
#define TILES_H (IMG_H / TH)             // 64
#define NBLOCKS (N_IMG * TILES_W * TILES_H)  // 6144
#define NCHUNK (LH * 66)                 // 792 float2 chunks per input (cols 0..131)

__device__ __forceinline__ int reflect_idx(int x, int n) {
    if (x < 0) return -x;
    if (x >= n) return 2 * n - 2 - x;
    return x;
}

__global__ void census_init(unsigned int* __restrict__ ws) {
    ws[0] = 0u;
    ws[1] = 0u;
}

__global__ __launch_bounds__(BLOCK, 4) void census_main(
    const float* __restrict__ pred, const float* __restrict__ gt,
    float* __restrict__ out, unsigned int* __restrict__ ws)
{
    __shared__ float lp[LH][LW];
    __shared__ float lg[LH][LW];

    const int b    = blockIdx.x;
    const int tw   = b & (TILES_W - 1);
    const int rest = b >> 2;
    const int th   = rest & (TILES_H - 1);
    const int img  = rest >> 6;
    const int w_base = tw * TW;
    const int h_base = th * TH;

    const float* __restrict__ pimg = pred + (size_t)img * IMG_H * IMG_W;
    const float* __restrict__ gimg = gt   + (size_t)img * IMG_H * IMG_W;

    const int tid = threadIdx.x;

    // ---- Phase 1: stage halo-materialized tile into LDS ----
    // LDS col j holds image col c = w_base + j - 2 (reflected), j in [0,132).
    for (unsigned int idx = tid; idx < NCHUNK; idx += BLOCK) {
        const int i  = idx / 66;         // LDS row 0..11
        const int cc = idx - i * 66;     // chunk 0..65
        const int j  = cc * 2;           // LDS col (even)
        const int c0 = w_base + j - 2;
        const int gy = reflect_idx(h_base - 2 + i, IMG_H);
        const float* __restrict__ prow = pimg + gy * IMG_W;
        const float* __restrict__ grow = gimg + gy * IMG_W;
        if (c0 >= 0 && c0 + 1 < IMG_W) {        // c0 even -> 8B aligned
            *(float2*)&lp[i][j] = *(const float2*)(prow + c0);
            *(float2*)&lg[i][j] = *(const float2*)(grow + c0);
        } else {
            const int r0 = reflect_idx(c0, IMG_W);
            const int r1 = reflect_idx(c0 + 1, IMG_W);
            lp[i][j]     = prow[r0];
            lp[i][j + 1] = prow[r1];
            lg[i][j]     = grow[r0];
            lg[i][j + 1] = grow[r1];
        }
    }
    __syncthreads();

    // ---- Phase 2: compute from LDS ----
    // thread -> 4-px strip: sc = tid&31 (strip col), rt = tid>>5 (row in tile)
    const int sc = tid & 31;
    const int rt = tid >> 5;
    const int j0 = sc * 4;   // LDS idx of window col w0-2  (16B aligned)

    // center row (dy==2): LDS row rt+2, window cols j0..j0+7
    float pcw[8], gcw[8];
    {
        float4 a = *(const float4*)&lp[rt + 2][j0];
        float4 c = *(const float4*)&lp[rt + 2][j0 + 4];
        pcw[0]=a.x; pcw[1]=a.y; pcw[2]=a.z; pcw[3]=a.w;
        pcw[4]=c.x; pcw[5]=c.y; pcw[6]=c.z; pcw[7]=c.w;
        float4 d = *(const float4*)&lg[rt + 2][j0];
        float4 e = *(const float4*)&lg[rt + 2][j0 + 4];
        gcw[0]=d.x; gcw[1]=d.y; gcw[2]=d.z; gcw[3]=d.w;
        gcw[4]=e.x; gcw[5]=e.y; gcw[6]=e.z; gcw[7]=e.w;
    }
    const float pc0 = pcw[2], pc1 = pcw[3], pc2 = pcw[4], pc3 = pcw[5];
    const float gc0 = gcw[2], gc1 = gcw[3], gc2 = gcw[4], gc3 = gcw[5];

    int cnt = 0;
    #pragma unroll
    for (int dy = 0; dy < 5; ++dy) {
        float pr[8], gr[8];
        if (dy == 2) {
            #pragma unroll
            for (int k = 0; k < 8; ++k) { pr[k] = pcw[k]; gr[k] = gcw[k]; }
        } else {
            float4 a = *(const float4*)&lp[rt + dy][j0];
            float4 c = *(const float4*)&lp[rt + dy][j0 + 4];
            pr[0]=a.x; pr[1]=a.y; pr[2]=a.z; pr[3]=a.w;
            pr[4]=c.x; pr[5]=c.y; pr[6]=c.z; pr[7]=c.w;
            float4 d = *(const float4*)&lg[rt + dy][j0];
            float4 e = *(const float4*)&lg[rt + dy][j0 + 4];
            gr[0]=d.x; gr[1]=d.y; gr[2]=d.z; gr[3]=d.w;
            gr[4]=e.x; gr[5]=e.y; gr[6]=e.z; gr[7]=e.w;
        }
        #pragma unroll
        for (int dx = 0; dx < 5; ++dx) {
            if (dy == 2 && dx == 2) continue;
            cnt += (int)((pr[0 + dx] < pc0) != (gr[0 + dx] < gc0));
            cnt += (int)((pr[1 + dx] < pc1) != (gr[1 + dx] < gc1));
            cnt += (int)((pr[2 + dx] < pc2) != (gr[2 + dx] < gc2));
            cnt += (int)((pr[3 + dx] < pc3) != (gr[3 + dx] < gc3));
        }
    }

    // ---- exact integer reduction ----
    #pragma unroll
    for (int off = 32; off > 0; off >>= 1)
        cnt += __shfl_down(cnt, off, 64);

    __shared__ int wave_sums[BLOCK / 64];
    const int lane = tid & 63;
    const int wid  = tid >> 6;
    if (lane == 0) wave_sums[wid] = cnt;
    __syncthreads();

    if (tid == 0) {
        int total = wave_sums[0] + wave_sums[1] + wave_sums[2] + wave_sums[3];
        atomicAdd(&ws[0], (unsigned int)total);
        __threadfence();
        unsigned int r = atomicAdd(&ws[1], 1u);
        if (r == (unsigned int)(NBLOCKS - 1)) {
            unsigned int tot = atomicAdd(&ws[0], 0u);
            out[0] = (float)((double)tot / (double)NPIX);
        }
    }
}

extern "C" void kernel_launch(void* const* d_in, const int* in_sizes, int n_in,
                              void* d_out, int out_size, void* d_ws, size_t ws_size,
                              hipStream_t stream) {
    const float* pred = (const float*)d_in[0];
    const float* gt   = (const float*)d_in[1];
    float* out        = (float*)d_out;
    unsigned int* ws  = (unsigned int*)d_ws;

    census_init<<<1, 1, 0, stream>>>(ws);
    census_main<<<NBLOCKS, BLOCK, 0, stream>>>(pred, gt, out, ws);
}

// Round 5
// 138.066 us; speedup vs baseline: 1.7730x; 1.7730x over previous
//
#include <hip/hip_runtime.h>

#define IMG_H 512
#define IMG_W 512
#define N_IMG 24                          // B*C
#define NPIX (N_IMG * IMG_H * IMG_W)      // 6291456
#define ROWS_PT 4                         // rows per thread
#define SLABS (IMG_H / ROWS_PT)           // 128
#define SCOLS (IMG_W / 4)                 // 128 strip-columns
#define BLOCK 256
#define NTHREADS (N_IMG * SLABS * SCOLS)  // 393216
#define NBLOCKS (NTHREADS / BLOCK)        // 1536

__device__ __forceinline__ int reflect_idx(int x, int n) {
    // jnp.pad 'reflect', PAD=2 -> single bounce
    if (x < 0) return -x;
    if (x >= n) return 2 * n - 2 - x;
    return x;
}

// Load the 8-float window (cols w0-2 .. w0+5, reflect-padded) of one row.
// Two dwordx4 loads at clamped IN-BOUNDS addresses (aL in [0,506], aR in
// [2,508]); edge fixup is register permutes (cndmask under the hood).
__device__ __forceinline__ void load_row(const float* __restrict__ row, int w0,
                                         float w[8]) {
    const int aL = (w0 == 0) ? 0 : ((w0 == 508) ? 506 : (w0 - 2));
    const int aR = (w0 == 0) ? 2 : ((w0 == 508) ? 508 : (w0 + 2));
    float4 A = *(const float4*)(row + aL);
    float4 B = *(const float4*)(row + aR);
    // interior: A = cols w0-2..w0+1, B = cols w0+2..w0+5
    w[0] = A.x; w[1] = A.y; w[2] = A.z; w[3] = A.w;
    w[4] = B.x; w[5] = B.y; w[6] = B.z; w[7] = B.w;
    if (w0 == 0) {
        // A = cols 0..3, B = cols 2..5 ; window [-2..5] -> [2,1,0,1,2,3,4,5]
        w[0] = A.z; w[1] = A.y; w[2] = A.x; w[3] = A.y;
        w[4] = A.z; w[5] = A.w; w[6] = B.z; w[7] = B.w;
    } else if (w0 == 508) {
        // A = 506..509, B = 508..511 ; window [506..513] -> [506..511, 510, 509]
        w[4] = B.z; w[5] = B.w; w[6] = B.z; w[7] = B.y;
    }
}

__global__ void census_init(unsigned int* __restrict__ ws) {
    ws[0] = 0u;
    ws[1] = 0u;
}

__global__ __launch_bounds__(BLOCK, 2) void census_main(
    const float* __restrict__ pred, const float* __restrict__ gt,
    float* __restrict__ out, unsigned int* __restrict__ ws)
{
    const int t    = blockIdx.x * BLOCK + threadIdx.x;
    const int sc   = t & (SCOLS - 1);       // strip column (consecutive lanes)
    const int rest = t >> 7;
    const int slab = rest & (SLABS - 1);
    const int img  = rest >> 7;
    const int w0   = sc * 4;
    const int h0   = slab * ROWS_PT;

    const float* __restrict__ pimg = pred + (size_t)img * IMG_H * IMG_W;
    const float* __restrict__ gimg = gt   + (size_t)img * IMG_H * IMG_W;

    // All 8 needed rows (h0-2 .. h0+5, reflected) of both inputs, upfront:
    // 32 independent dwordx4 loads -> one latency drain, then pure VALU.
    float pw[ROWS_PT + 4][8], gw[ROWS_PT + 4][8];
    #pragma unroll
    for (int i = 0; i < ROWS_PT + 4; ++i) {
        const int ry = reflect_idx(h0 - 2 + i, IMG_H);
        load_row(pimg + ry * IMG_W, w0, pw[i]);
        load_row(gimg + ry * IMG_W, w0, gw[i]);
    }

    int cnt = 0;
    #pragma unroll
    for (int r = 0; r < ROWS_PT; ++r) {
        const float pc0 = pw[r + 2][2], pc1 = pw[r + 2][3],
                    pc2 = pw[r + 2][4], pc3 = pw[r + 2][5];
        const float gc0 = gw[r + 2][2], gc1 = gw[r + 2][3],
                    gc2 = gw[r + 2][4], gc3 = gw[r + 2][5];
        #pragma unroll
        for (int dy = 0; dy < 5; ++dy) {
            const int row = r + dy;
            #pragma unroll
            for (int dx = 0; dx < 5; ++dx) {
                if (dy == 2 && dx == 2) continue;   // window center
                cnt += (int)((pw[row][0 + dx] < pc0) != (gw[row][0 + dx] < gc0));
                cnt += (int)((pw[row][1 + dx] < pc1) != (gw[row][1 + dx] < gc1));
                cnt += (int)((pw[row][2 + dx] < pc2) != (gw[row][2 + dx] < gc2));
                cnt += (int)((pw[row][3 + dx] < pc3) != (gw[row][3 + dx] < gc3));
            }
        }
    }

    // ---- exact integer reduction ----
    #pragma unroll
    for (int off = 32; off > 0; off >>= 1)
        cnt += __shfl_down(cnt, off, 64);

    __shared__ int wave_sums[BLOCK / 64];
    const int lane = threadIdx.x & 63;
    const int wid  = threadIdx.x >> 6;
    if (lane == 0) wave_sums[wid] = cnt;
    __syncthreads();

    if (threadIdx.x == 0) {
        int total = wave_sums[0] + wave_sums[1] + wave_sums[2] + wave_sums[3];
        atomicAdd(&ws[0], (unsigned int)total);
        __threadfence();
        unsigned int r = atomicAdd(&ws[1], 1u);
        if (r == (unsigned int)(NBLOCKS - 1)) {
            unsigned int tot = atomicAdd(&ws[0], 0u);
            out[0] = (float)((double)tot / (double)NPIX);
        }
    }
}

extern "C" void kernel_launch(void* const* d_in, const int* in_sizes, int n_in,
                              void* d_out, int out_size, void* d_ws, size_t ws_size,
                              hipStream_t stream) {
    const float* pred = (const float*)d_in[0];
    const float* gt   = (const float*)d_in[1];
    float* out        = (float*)d_out;
    unsigned int* ws  = (unsigned int*)d_ws;

    census_init<<<1, 1, 0, stream>>>(ws);
    census_main<<<NBLOCKS, BLOCK, 0, stream>>>(pred, gt, out, ws);
}

// Round 6
// 131.468 us; speedup vs baseline: 1.8620x; 1.0502x over previous
//
#include <hip/hip_runtime.h>

#define IMG_H 512
#define IMG_W 512
#define N_IMG 24                          // B*C
#define NPIX (N_IMG * IMG_H * IMG_W)      // 6291456
#define ROWS_PT 8                         // rows per thread
#define SLABS (IMG_H / ROWS_PT)           // 64
#define SCOLS (IMG_W / 4)                 // 128 strip-columns
#define BLOCK 256
#define NTHREADS (N_IMG * SLABS * SCOLS)  // 196608
#define NBLOCKS (NTHREADS / BLOCK)        // 768
#define SLOTS 7                           // 5-row window + prefetch distance 2

__device__ __forceinline__ int reflect_idx(int x, int n) {
    // jnp.pad 'reflect', PAD=2 -> single bounce
    if (x < 0) return -x;
    if (x >= n) return 2 * n - 2 - x;
    return x;
}

// Load the 8-float window (cols w0-2 .. w0+5, reflect-padded) of one row.
// Two dwordx4 loads at clamped IN-BOUNDS addresses (aL in [0,506], aR in
// [2,508]); edge fixup is register selects.
__device__ __forceinline__ void load_row(const float* __restrict__ row, int w0,
                                         float w[8]) {
    const int aL = (w0 == 0) ? 0 : ((w0 == 508) ? 506 : (w0 - 2));
    const int aR = (w0 == 0) ? 2 : ((w0 == 508) ? 508 : (w0 + 2));
    float4 A = *(const float4*)(row + aL);
    float4 B = *(const float4*)(row + aR);
    // interior: A = cols w0-2..w0+1, B = cols w0+2..w0+5
    w[0] = A.x; w[1] = A.y; w[2] = A.z; w[3] = A.w;
    w[4] = B.x; w[5] = B.y; w[6] = B.z; w[7] = B.w;
    if (w0 == 0) {
        // A = cols 0..3, B = cols 2..5 ; window [-2..5] -> [2,1,0,1,2,3,4,5]
        w[0] = A.z; w[1] = A.y; w[2] = A.x; w[3] = A.y;
        w[4] = A.z; w[5] = A.w; w[6] = B.z; w[7] = B.w;
    } else if (w0 == 508) {
        // A = 506..509, B = 508..511 ; window [506..513] -> [506..511, 510, 509]
        w[4] = B.z; w[5] = B.w; w[6] = B.z; w[7] = B.y;
    }
}

__global__ void census_init(unsigned int* __restrict__ ws) {
    ws[0] = 0u;
    ws[1] = 0u;
}

__global__ __launch_bounds__(BLOCK, 2) void census_main(
    const float* __restrict__ pred, const float* __restrict__ gt,
    float* __restrict__ out, unsigned int* __restrict__ ws)
{
    const int t    = blockIdx.x * BLOCK + threadIdx.x;
    const int sc   = t & (SCOLS - 1);       // strip column (consecutive lanes)
    const int rest = t >> 7;
    const int slab = rest & (SLABS - 1);
    const int img  = rest >> 6;
    const int w0   = sc * 4;
    const int h0   = slab * ROWS_PT;

    const float* __restrict__ pimg = pred + (size_t)img * IMG_H * IMG_W;
    const float* __restrict__ gimg = gt   + (size_t)img * IMG_H * IMG_W;

    // 7-slot rolling ring: row h0+k-2 lives in slot k%7.
    float pw[SLOTS][8], gw[SLOTS][8];

    // Preload rows h0-2 .. h0+3 (slots 0..5).
    #pragma unroll
    for (int k = 0; k < 6; ++k) {
        const int ry = reflect_idx(h0 - 2 + k, IMG_H);
        load_row(pimg + ry * IMG_W, w0, pw[k]);
        load_row(gimg + ry * IMG_W, w0, gw[k]);
    }

    int c0 = 0, c1 = 0, c2 = 0, c3 = 0;

    #pragma unroll
    for (int r = 0; r < ROWS_PT; ++r) {
        // Prefetch row h0+r+4 (needed first at iteration r+2) into the slot
        // whose row (h0+r-3) was last used at iteration r-1.
        if (r <= ROWS_PT - 3) {
            const int ry = reflect_idx(h0 + r + 4, IMG_H);
            load_row(pimg + ry * IMG_W, w0, pw[(r + 6) % SLOTS]);
            load_row(gimg + ry * IMG_W, w0, gw[(r + 6) % SLOTS]);
        }

        // Window rows h0+r-2 .. h0+r+2 = slots (r+0)%7 .. (r+4)%7, all loaded
        // >= 2 iterations ago. Center row slot (r+2)%7.
        const int cs = (r + 2) % SLOTS;
        const float pc0 = pw[cs][2], pc1 = pw[cs][3], pc2 = pw[cs][4], pc3 = pw[cs][5];
        const float gc0 = gw[cs][2], gc1 = gw[cs][3], gc2 = gw[cs][4], gc3 = gw[cs][5];

        #pragma unroll
        for (int dy = 0; dy < 5; ++dy) {
            const int wr = (r + dy) % SLOTS;
            #pragma unroll
            for (int dx = 0; dx < 5; ++dx) {
                if (dy == 2 && dx == 2) continue;   // window center
                c0 += (int)((pw[wr][0 + dx] < pc0) != (gw[wr][0 + dx] < gc0));
                c1 += (int)((pw[wr][1 + dx] < pc1) != (gw[wr][1 + dx] < gc1));
                c2 += (int)((pw[wr][2 + dx] < pc2) != (gw[wr][2 + dx] < gc2));
                c3 += (int)((pw[wr][3 + dx] < pc3) != (gw[wr][3 + dx] < gc3));
            }
        }
    }

    int cnt = (c0 + c1) + (c2 + c3);

    // ---- exact integer reduction ----
    #pragma unroll
    for (int off = 32; off > 0; off >>= 1)
        cnt += __shfl_down(cnt, off, 64);

    __shared__ int wave_sums[BLOCK / 64];
    const int lane = threadIdx.x & 63;
    const int wid  = threadIdx.x >> 6;
    if (lane == 0) wave_sums[wid] = cnt;
    __syncthreads();

    if (threadIdx.x == 0) {
        int total = wave_sums[0] + wave_sums[1] + wave_sums[2] + wave_sums[3];
        atomicAdd(&ws[0], (unsigned int)total);
        __threadfence();
        unsigned int r = atomicAdd(&ws[1], 1u);
        if (r == (unsigned int)(NBLOCKS - 1)) {
            unsigned int tot = atomicAdd(&ws[0], 0u);
            out[0] = (float)((double)tot / (double)NPIX);
        }
    }
}

extern "C" void kernel_launch(void* const* d_in, const int* in_sizes, int n_in,
                              void* d_out, int out_size, void* d_ws, size_t ws_size,
                              hipStream_t stream) {
    const float* pred = (const float*)d_in[0];
    const float* gt   = (const float*)d_in[1];
    float* out        = (float*)d_out;
    unsigned int* ws  = (unsigned int*)d_ws;

    census_init<<<1, 1, 0, stream>>>(ws);
    census_main<<<NBLOCKS, BLOCK, 0, stream>>>(pred, gt, out, ws);
}

// Round 7
// 127.618 us; speedup vs baseline: 1.9182x; 1.0302x over previous
//
#include <hip/hip_runtime.h>

#define IMG_H 512
#define IMG_W 512
#define N_IMG 24                          // B*C
#define NPIX (N_IMG * IMG_H * IMG_W)      // 6291456
#define ROWS_PT 4                         // rows per thread
#define NROWS (ROWS_PT + 4)               // 8 loaded rows per input
#define SLABS (IMG_H / ROWS_PT)           // 128
#define SCOLS (IMG_W / 4)                 // 128 strip-columns
#define BLOCK 256
#define NTHREADS (N_IMG * SLABS * SCOLS)  // 393216
#define NBLOCKS (NTHREADS / BLOCK)        // 1536

__device__ __forceinline__ int reflect_idx(int x, int n) {
    // jnp.pad 'reflect', PAD=2 -> single bounce
    if (x < 0) return -x;
    if (x >= n) return 2 * n - 2 - x;
    return x;
}

// Post-load fixup: turn raw A (cols aL..aL+3) / B (cols aR..aR+3) into the
// 8-float window (cols w0-2 .. w0+5, reflect-padded). Pure register permutes.
__device__ __forceinline__ void fix_row(float4 A, float4 B, int w0, float w[8]) {
    // interior: A = cols w0-2..w0+1, B = cols w0+2..w0+5
    w[0] = A.x; w[1] = A.y; w[2] = A.z; w[3] = A.w;
    w[4] = B.x; w[5] = B.y; w[6] = B.z; w[7] = B.w;
    if (w0 == 0) {
        // A = cols 0..3, B = cols 2..5 ; window [-2..5] -> [2,1,0,1,2,3,4,5]
        w[0] = A.z; w[1] = A.y; w[2] = A.x; w[3] = A.y;
        w[4] = A.z; w[5] = A.w; w[6] = B.z; w[7] = B.w;
    } else if (w0 == 508) {
        // A = 506..509, B = 508..511 ; window [506..513] -> [506..511,510,509]
        w[4] = B.z; w[5] = B.w; w[6] = B.z; w[7] = B.y;
    }
}

__global__ void census_init(unsigned int* __restrict__ ws) {
    ws[0] = 0u;
    ws[1] = 0u;
}

__global__ __launch_bounds__(BLOCK, 2) void census_main(
    const float* __restrict__ pred, const float* __restrict__ gt,
    float* __restrict__ out, unsigned int* __restrict__ ws)
{
    const int t    = blockIdx.x * BLOCK + threadIdx.x;
    const int sc   = t & (SCOLS - 1);       // strip column (consecutive lanes)
    const int rest = t >> 7;
    const int slab = rest & (SLABS - 1);
    const int img  = rest >> 7;
    const int w0   = sc * 4;
    const int h0   = slab * ROWS_PT;

    const float* __restrict__ pimg = pred + (size_t)img * IMG_H * IMG_W;
    const float* __restrict__ gimg = gt   + (size_t)img * IMG_H * IMG_W;

    // Clamped in-bounds load addresses (aL in [0,506], aR in [2,508]).
    const int aL = (w0 == 0) ? 0 : ((w0 == 508) ? 506 : (w0 - 2));
    const int aR = (w0 == 0) ? 2 : ((w0 == 508) ? 508 : (w0 + 2));

    // ---- Phase 1: issue ALL 32 dwordx4 loads, no consumption ----
    float4 pA[NROWS], pB[NROWS], gA[NROWS], gB[NROWS];
    #pragma unroll
    for (int i = 0; i < NROWS; ++i) {
        const int ry = reflect_idx(h0 - 2 + i, IMG_H);
        const float* __restrict__ prow = pimg + ry * IMG_W;
        const float* __restrict__ grow = gimg + ry * IMG_W;
        pA[i] = *(const float4*)(prow + aL);
        pB[i] = *(const float4*)(prow + aR);
        gA[i] = *(const float4*)(grow + aL);
        gB[i] = *(const float4*)(grow + aR);
    }

    // Pin the schedule: nothing crosses. All 32 loads are now in flight and
    // their results forcibly live -> compute phase gets partial vmcnt waits.
    __builtin_amdgcn_sched_barrier(0);

    // ---- Phase 2: fixup + compute (consumes rows in order) ----
    float pw[NROWS][8], gw[NROWS][8];
    #pragma unroll
    for (int i = 0; i < NROWS; ++i) {
        fix_row(pA[i], pB[i], w0, pw[i]);
        fix_row(gA[i], gB[i], w0, gw[i]);
    }

    int c0 = 0, c1 = 0, c2 = 0, c3 = 0;
    #pragma unroll
    for (int r = 0; r < ROWS_PT; ++r) {
        const float pc0 = pw[r + 2][2], pc1 = pw[r + 2][3],
                    pc2 = pw[r + 2][4], pc3 = pw[r + 2][5];
        const float gc0 = gw[r + 2][2], gc1 = gw[r + 2][3],
                    gc2 = gw[r + 2][4], gc3 = gw[r + 2][5];
        #pragma unroll
        for (int dy = 0; dy < 5; ++dy) {
            const int row = r + dy;
            #pragma unroll
            for (int dx = 0; dx < 5; ++dx) {
                if (dy == 2 && dx == 2) continue;   // window center
                c0 += (int)((pw[row][0 + dx] < pc0) != (gw[row][0 + dx] < gc0));
                c1 += (int)((pw[row][1 + dx] < pc1) != (gw[row][1 + dx] < gc1));
                c2 += (int)((pw[row][2 + dx] < pc2) != (gw[row][2 + dx] < gc2));
                c3 += (int)((pw[row][3 + dx] < pc3) != (gw[row][3 + dx] < gc3));
            }
        }
    }
    int cnt = (c0 + c1) + (c2 + c3);

    // ---- exact integer reduction ----
    #pragma unroll
    for (int off = 32; off > 0; off >>= 1)
        cnt += __shfl_down(cnt, off, 64);

    __shared__ int wave_sums[BLOCK / 64];
    const int lane = threadIdx.x & 63;
    const int wid  = threadIdx.x >> 6;
    if (lane == 0) wave_sums[wid] = cnt;
    __syncthreads();

    if (threadIdx.x == 0) {
        int total = wave_sums[0] + wave_sums[1] + wave_sums[2] + wave_sums[3];
        atomicAdd(&ws[0], (unsigned int)total);
        __threadfence();
        unsigned int r = atomicAdd(&ws[1], 1u);
        if (r == (unsigned int)(NBLOCKS - 1)) {
            unsigned int tot = atomicAdd(&ws[0], 0u);
            out[0] = (float)((double)tot / (double)NPIX);
        }
    }
}

extern "C" void kernel_launch(void* const* d_in, const int* in_sizes, int n_in,
                              void* d_out, int out_size, void* d_ws, size_t ws_size,
                              hipStream_t stream) {
    const float* pred = (const float*)d_in[0];
    const float* gt   = (const float*)d_in[1];
    float* out        = (float*)d_out;
    unsigned int* ws  = (unsigned int*)d_ws;

    census_init<<<1, 1, 0, stream>>>(ws);
    census_main<<<NBLOCKS, BLOCK, 0, stream>>>(pred, gt, out, ws);
}

// Round 9
// 127.083 us; speedup vs baseline: 1.9262x; 1.0042x over previous
//
#include <hip/hip_runtime.h>

#define IMG_H 512
#define IMG_W 512
#define N_IMG 24                          // B*C
#define NPIX (N_IMG * IMG_H * IMG_W)      // 6291456
#define ROWS_PT 4                         // rows per thread
#define NROWS 8                           // loaded rows per input
#define SLABS (IMG_H / ROWS_PT)           // 128
#define SCOLS (IMG_W / 4)                 // 128 strip-columns
#define BLOCK 256
#define NBLOCKS ((N_IMG * SLABS * SCOLS) / BLOCK)  // 1536

// Partial vmem wait + hard scheduler fence (keeps consumers below the wait).
#define VMWAIT(N)                                             \
    asm volatile("s_waitcnt vmcnt(" #N ")" ::: "memory");     \
    __builtin_amdgcn_sched_barrier(0)

// Branchless reflect for PAD=2: min(|x|, 2H-2-|x|)
__device__ __forceinline__ int reflect_b(int x) {
    int a = x < 0 ? -x : x;
    int b = 2 * IMG_H - 2 - a;
    return a < b ? a : b;
}

// Raw 16B load via volatile asm: no compiler waitcnt, immovable at IR level,
// program-ordered against the VMWAIT asms.
__device__ __forceinline__ float4 gload4(const float* p) {
    float4 r;
    asm volatile("global_load_dwordx4 %0, %1, off" : "=v"(r) : "v"(p));
    return r;
}

// Branchless fixup: raw A (cols aL..aL+3) / B (cols aR..aR+3) -> 8-float
// window (cols w0-2..w0+5, reflect-padded). Pure cndmask selects.
__device__ __forceinline__ void fix_row(float4 A, float4 B, int w0, float w[8]) {
    const bool e0 = (w0 == 0);
    const bool e5 = (w0 == 508);
    w[0] = e0 ? A.z : A.x;
    w[1] = A.y;
    w[2] = e0 ? A.x : A.z;
    w[3] = e0 ? A.y : A.w;
    w[4] = e0 ? A.z : (e5 ? B.z : B.x);
    w[5] = e0 ? A.w : (e5 ? B.w : B.y);
    w[6] = B.z;
    w[7] = e5 ? B.y : B.w;
}

#define DO_ROW(R)                                                              \
    {                                                                          \
        const float pc0 = pw[(R) + 2][2], pc1 = pw[(R) + 2][3],                \
                    pc2 = pw[(R) + 2][4], pc3 = pw[(R) + 2][5];                \
        const float gc0 = gw[(R) + 2][2], gc1 = gw[(R) + 2][3],                \
                    gc2 = gw[(R) + 2][4], gc3 = gw[(R) + 2][5];                \
        _Pragma("unroll")                                                      \
        for (int dy = 0; dy < 5; ++dy) {                                       \
            const int row = (R) + dy;                                          \
            _Pragma("unroll")                                                  \
            for (int dx = 0; dx < 5; ++dx) {                                   \
                if (dy == 2 && dx == 2) continue;                              \
                c0 += (int)((pw[row][0 + dx] < pc0) != (gw[row][0 + dx] < gc0)); \
                c1 += (int)((pw[row][1 + dx] < pc1) != (gw[row][1 + dx] < gc1)); \
                c2 += (int)((pw[row][2 + dx] < pc2) != (gw[row][2 + dx] < gc2)); \
                c3 += (int)((pw[row][3 + dx] < pc3) != (gw[row][3 + dx] < gc3)); \
            }                                                                  \
        }                                                                      \
    }

__global__ void census_init(unsigned int* __restrict__ ws) {
    ws[0] = 0u;
    ws[1] = 0u;
}

__global__ __launch_bounds__(BLOCK, 2) void census_main(
    const float* __restrict__ pred, const float* __restrict__ gt,
    float* __restrict__ out, unsigned int* __restrict__ ws)
{
    const int t    = blockIdx.x * BLOCK + threadIdx.x;
    const int sc   = t & (SCOLS - 1);       // strip column (consecutive lanes)
    const int rest = t >> 7;
    const int slab = rest & (SLABS - 1);
    const int img  = rest >> 7;
    const int w0   = sc * 4;
    const int h0   = slab * ROWS_PT;

    const float* __restrict__ pimg = pred + (size_t)img * IMG_H * IMG_W;
    const float* __restrict__ gimg = gt   + (size_t)img * IMG_H * IMG_W;

    // Branchless clamped in-bounds addresses (aL in [0,506], aR in [2,508]).
    const int aL = max(0, min(w0 - 2, IMG_W - 6));
    const int aR = max(2, min(w0 + 2, IMG_W - 4));

    // ---- issue ALL 32 loads (4 per row: pA,pB,gA,gB), volatile order ----
    float4 pA[NROWS], pB[NROWS], gA[NROWS], gB[NROWS];
    #pragma unroll
    for (int i = 0; i < NROWS; ++i) {
        const int ry = reflect_b(h0 - 2 + i);
        const float* prow = pimg + ry * IMG_W;
        const float* grow = gimg + ry * IMG_W;
        pA[i] = gload4(prow + aL);
        pB[i] = gload4(prow + aR);
        gA[i] = gload4(grow + aL);
        gB[i] = gload4(grow + aR);
    }
    __builtin_amdgcn_sched_barrier(0);

    float pw[NROWS][8], gw[NROWS][8];
    int c0 = 0, c1 = 0, c2 = 0, c3 = 0;

    // rows 0,1 landed (loads 0..7 retired; <=24 outstanding)
    VMWAIT(24);
    fix_row(pA[0], pB[0], w0, pw[0]); fix_row(gA[0], gB[0], w0, gw[0]);
    fix_row(pA[1], pB[1], w0, pw[1]); fix_row(gA[1], gB[1], w0, gw[1]);

    // rows 2,3,4 landed (<=12 outstanding)
    VMWAIT(12);
    fix_row(pA[2], pB[2], w0, pw[2]); fix_row(gA[2], gB[2], w0, gw[2]);
    fix_row(pA[3], pB[3], w0, pw[3]); fix_row(gA[3], gB[3], w0, gw[3]);
    fix_row(pA[4], pB[4], w0, pw[4]); fix_row(gA[4], gB[4], w0, gw[4]);
    DO_ROW(0)            // rows 5..7 still in flight

    VMWAIT(8);
    fix_row(pA[5], pB[5], w0, pw[5]); fix_row(gA[5], gB[5], w0, gw[5]);
    DO_ROW(1)

    VMWAIT(4);
    fix_row(pA[6], pB[6], w0, pw[6]); fix_row(gA[6], gB[6], w0, gw[6]);
    DO_ROW(2)

    VMWAIT(0);
    fix_row(pA[7], pB[7], w0, pw[7]); fix_row(gA[7], gB[7], w0, gw[7]);
    DO_ROW(3)

    int cnt = (c0 + c1) + (c2 + c3);

    // ---- exact integer reduction ----
    #pragma unroll
    for (int off = 32; off > 0; off >>= 1)
        cnt += __shfl_down(cnt, off, 64);

    __shared__ int wave_sums[BLOCK / 64];
    const int lane = threadIdx.x & 63;
    const int wid  = threadIdx.x >> 6;
    if (lane == 0) wave_sums[wid] = cnt;
    __syncthreads();

    if (threadIdx.x == 0) {
        int total = wave_sums[0] + wave_sums[1] + wave_sums[2] + wave_sums[3];
        atomicAdd(&ws[0], (unsigned int)total);
        __threadfence();
        unsigned int r = atomicAdd(&ws[1], 1u);
        if (r == (unsigned int)(NBLOCKS - 1)) {
            unsigned int tot = atomicAdd(&ws[0], 0u);
            out[0] = (float)((double)tot / (double)NPIX);
        }
    }
}

extern "C" void kernel_launch(void* const* d_in, const int* in_sizes, int n_in,
                              void* d_out, int out_size, void* d_ws, size_t ws_size,
                              hipStream_t stream) {
    const float* pred = (const float*)d_in[0];
    const float* gt   = (const float*)d_in[1];
    float* out        = (float*)d_out;
    unsigned int* ws  = (unsigned int*)d_ws;

    census_init<<<1, 1, 0, stream>>>(ws);
    census_main<<<NBLOCKS, BLOCK, 0, stream>>>(pred, gt, out, ws);
}